// Round 14
// baseline (387.259 us; speedup 1.0000x reference)
//
#include <hip/hip_runtime.h>
#include <math.h>

#define B_TOT 2048
#define T_LEN 256
#define D_IN  131
#define NTHR  768   // 12 waves: 0-7 = layer1, 8-11 = layer2(+1-step lag) + staging

typedef __attribute__((ext_vector_type(8))) short s16x8;
typedef __attribute__((ext_vector_type(4))) float f32x4;

#define MFMA_B16(a,b,c) __builtin_amdgcn_mfma_f32_16x16x32_bf16(a, b, c, 0, 0, 0)

// LDS geometry (shorts)
#define PLX   (2*32*168)   // one x buffer: [plane(hi/lo)][32 rows][168]
#define PLH1  (24*72)      // h1: rows 0-7 hi, 8-15 lo, 16-23 zero
#define PLH2  (24*40)

// ws layout (shorts): wih1 hi/lo [2][256][160] @0 (k=131 col = folded bias);
// whh1 hi/lo @81920 ; w2 hi/lo @114688 (k<64 = W_ih2, k>=64 = W_hh2)
#define WS_WIH1_LO 40960
#define WS_WHH1    81920
#define WS_W2      114688
#define PREP_N     (40960 + 16384 + 12288)

__device__ __forceinline__ float rcp_(float x){ return __builtin_amdgcn_rcpf(x); }
__device__ __forceinline__ float sigmoidf_(float x){ return rcp_(1.0f + __expf(-x)); }
__device__ __forceinline__ float tanhf_(float x){
    float ax = fabsf(x);
    float e  = __expf(-2.0f * ax);
    float t  = (1.0f - e) * rcp_(1.0f + e);
    return copysignf(t, x);
}
__device__ __forceinline__ unsigned short bfrne(float f){
    unsigned u = __float_as_uint(f);
    return (unsigned short)((u + 0x7fffu + ((u>>16)&1u)) >> 16);
}
__device__ __forceinline__ float bf2f(unsigned short h){
    return __uint_as_float(((unsigned)h)<<16);
}

// Column permutation: tile col packs [i-units(8) | f-units(8)] / [g | o] per wave.
__global__ void prep_w(const float* __restrict__ W_ih1, const float* __restrict__ W_hh1,
                       const float* __restrict__ W_ih2, const float* __restrict__ W_hh2,
                       const float* __restrict__ b_ih1, const float* __restrict__ b_hh1,
                       short* __restrict__ wsS) {
    int i = blockIdx.x*256 + threadIdx.x;
    if (i >= PREP_N) return;
    if (i < 40960) {                       // W_ih1 hi/lo: [n'][160], k=131 -> bias
        int np = i / 160, k = i - np*160;
        int u = (np>>5)*8 + (np&7);
        int gate = ((np>>4)&1)*2 + ((np>>3)&1);
        int n = gate*64 + u;
        float v;
        if (k < D_IN)       v = W_ih1[n*D_IN + k];
        else if (k == D_IN) v = b_ih1[n] + b_hh1[n];
        else                v = 0.0f;
        unsigned short hi = bfrne(v);
        wsS[i]              = (short)hi;
        wsS[WS_WIH1_LO + i] = (short)bfrne(v - bf2f(hi));
    } else if (i < 40960 + 16384) {        // W_hh1 hi/lo: [n'][64]
        int j = i - 40960;
        int np = j >> 6, k = j & 63;
        int u = (np>>5)*8 + (np&7);
        int gate = ((np>>4)&1)*2 + ((np>>3)&1);
        int n = gate*64 + u;
        float v = W_hh1[n*64 + k];
        unsigned short hi = bfrne(v);
        wsS[WS_WHH1 + j]         = (short)hi;
        wsS[WS_WHH1 + 16384 + j] = (short)bfrne(v - bf2f(hi));
    } else {                               // W_ih2|W_hh2 hi/lo: [n'][96]
        int j = i - (40960 + 16384);
        int np = j / 96, k = j - np*96;
        int u = ((np>>5)&3)*8 + (np&7);
        int gate = ((np>>4)&1)*2 + ((np>>3)&1);
        int n = gate*32 + u;
        float v = (k < 64) ? W_ih2[n*64 + k] : W_hh2[n*32 + (k - 64)];
        unsigned short hi = bfrne(v);
        wsS[WS_W2 + j]         = (short)hi;
        wsS[WS_W2 + 12288 + j] = (short)bfrne(v - bf2f(hi));
    }
}

// ---- PHASE1 (waves 0-7): layer-1, N=32 cols/wave. Rec MFMAs in 4 PARALLEL
// short chains (rP,sP 4-deep; rQ,sQ 2-deep) into fresh accumulators; sum with
// the pristine in-proj accw at scatter. (R12 had 6-deep chains into accw —
// dependent-MFMA latency stacked on the critical path.)
#define PHASE1(U, P) do { \
  const short* h1r = h1bf + (P)*PLH1; \
  short*       h1w = h1bf + (1-(P))*PLH1; \
  const int rH = (r & 7) + 16*(((r >> 3) ^ (P)) & 1); \
  const int rL = 8 + (r & 7) + 8*(((r >> 3) ^ (P)) & 1); \
  s16x8 ah0 = *(const s16x8*)&h1r[rH*72 + g4*8]; \
  s16x8 ah1 = *(const s16x8*)&h1r[rH*72 + 32 + g4*8]; \
  s16x8 al0 = *(const s16x8*)&h1r[rL*72 + g4*8]; \
  s16x8 al1 = *(const s16x8*)&h1r[rL*72 + 32 + g4*8]; \
  f32x4 rP = zero4, rQ = zero4, sP = zero4, sQ = zero4; \
  rP = MFMA_B16(ah0, whf[0][0][0], rP);  sP = MFMA_B16(ah0, whf[1][0][0], sP); \
  rQ = MFMA_B16(ah0, whf[0][0][1], rQ);  sQ = MFMA_B16(ah0, whf[1][0][1], sQ); \
  rP = MFMA_B16(ah1, whf[0][1][0], rP);  sP = MFMA_B16(ah1, whf[1][1][0], sP); \
  rQ = MFMA_B16(ah1, whf[0][1][1], rQ);  sQ = MFMA_B16(ah1, whf[1][1][1], sQ); \
  rP = MFMA_B16(al0, whf[0][0][0], rP);  sP = MFMA_B16(al0, whf[1][0][0], sP); \
  rP = MFMA_B16(al1, whf[0][1][0], rP);  sP = MFMA_B16(al1, whf[1][1][0], sP); \
  if ((g4 >> 1) == (P)) { \
    *(f32x4*)(gw0 + 4*(g4 & 1)) = accw[U][0] + rP + rQ; \
    *(f32x4*)(gw1 + 4*(g4 & 1)) = accw[U][1] + sP + sQ; \
  } \
  float gi = sigmoidf_(gp[0]);     /* bias folded via k=131 column */ \
  float gf = sigmoidf_(gp[64]); \
  float gg = tanhf_   (gp[128]); \
  float go = sigmoidf_(gp[192]); \
  c1 = gf * c1 + gi * gg; \
  float hv = go * tanhf_(c1); \
  unsigned short hh = bfrne(hv); \
  h1w[bq*72 + u1g]     = (short)hh; \
  h1w[(8+bq)*72 + u1g] = (short)bfrne(hv - bf2f(hh)); \
} while(0)

// ---- PHASE2 (waves 8-11): layer-2 one step behind; 6 PARALLEL 3-deep chains
// (was two 9-deep chains -- which made the L2 wave the interval's critical path).
#define PHASE2(P) do { \
  const short* h1n = h1bf + (1-(P))*PLH1; \
  const short* h2r = h2bf + (P)*PLH2; \
  short*       h2w = h2bf + (1-(P))*PLH2; \
  const int rH2 = (r & 7) + 16*(r >> 3); \
  const int rL2 = 8 + (r & 7) + 8*(r >> 3); \
  s16x8 ah0 = *(const s16x8*)&h1n[rH2*72 + g4*8]; \
  s16x8 ah1 = *(const s16x8*)&h1n[rH2*72 + 32 + g4*8]; \
  s16x8 al0 = *(const s16x8*)&h1n[rL2*72 + g4*8]; \
  s16x8 al1 = *(const s16x8*)&h1n[rL2*72 + 32 + g4*8]; \
  s16x8 bh  = *(const s16x8*)&h2r[rH2*40 + g4*8]; \
  s16x8 bl  = *(const s16x8*)&h2r[rL2*40 + g4*8]; \
  f32x4 pA = zero4, pB = zero4, pC = zero4; \
  f32x4 qA = zero4, qB = zero4, qC = zero4; \
  pA = MFMA_B16(ah0, w2f[0][0][0], pA);  qA = MFMA_B16(ah0, w2f[1][0][0], qA); \
  pB = MFMA_B16(ah0, w2f[0][0][1], pB);  qB = MFMA_B16(ah0, w2f[1][0][1], qB); \
  pC = MFMA_B16(al0, w2f[0][0][0], pC);  qC = MFMA_B16(al0, w2f[1][0][0], qC); \
  pA = MFMA_B16(ah1, w2f[0][1][0], pA);  qA = MFMA_B16(ah1, w2f[1][1][0], qA); \
  pB = MFMA_B16(ah1, w2f[0][1][1], pB);  qB = MFMA_B16(ah1, w2f[1][1][1], qB); \
  pC = MFMA_B16(al1, w2f[0][1][0], pC);  qC = MFMA_B16(al1, w2f[1][1][0], qC); \
  pA = MFMA_B16(bh,  w2f[0][2][0], pA);  qA = MFMA_B16(bh,  w2f[1][2][0], qA); \
  pB = MFMA_B16(bh,  w2f[0][2][1], pB);  qB = MFMA_B16(bh,  w2f[1][2][1], qB); \
  pC = MFMA_B16(bl,  w2f[0][2][0], pC);  qC = MFMA_B16(bl,  w2f[1][2][0], qC); \
  if (g4 < 2) { \
    *(f32x4*)(gw0 + 4*g4) = pA + pB + pC; \
    *(f32x4*)(gw1 + 4*g4) = qA + qB + qC; \
  } \
  float gi = sigmoidf_(gp[0]   + l2bi); \
  float gf = sigmoidf_(gp[64]  + l2bf); \
  float gg = tanhf_   (gp[128] + l2bg); \
  float go = sigmoidf_(gp[192] + l2bo); \
  c2 = gf * c2 + gi * gg; \
  float hv = go * tanhf_(c2); \
  h2last = hv; \
  unsigned short hh = bfrne(hv); \
  h2w[bq*40 + u2i]     = (short)hh; \
  h2w[(8+bq)*40 + u2i] = (short)bfrne(hv - bf2f(hh)); \
} while(0)

// ---- STAGE (waves 8-11, 256 lanes): write chunk S of next window, prefetch.
#define STAGE(S) do { \
  if (w0 < 63) { \
    _Pragma("unroll") \
    for (int m = 0; m < 5; ++m) { \
      if (m < 4 || sv4) { \
        int mrow = (S)*8 + runm[m]; \
        unsigned short hh = bfrne(xr[m]); \
        xn[mrow*168 + km[m]]      = (short)hh; \
        xn[(32+mrow)*168 + km[m]] = (short)bfrne(xr[m] - bf2f(hh)); \
      } \
    } \
    if ((S) < 3 || w0 <= 61) { \
      int tl = ((S) < 3) ? ((w0+1)*4 + (S) + 1) : ((w0+2)*4); \
      _Pragma("unroll") \
      for (int m = 0; m < 5; ++m) \
        if (m < 4 || sv4) xr[m] = x[(size_t)(offm[m] + tl*131)]; \
    } \
  } \
} while(0)

__global__ __launch_bounds__(NTHR, 1) void lstm_mfma(
    const float* __restrict__ x,
    const short* __restrict__ wsS,
    const float* __restrict__ b_ih2, const float* __restrict__ b_hh2,
    const float* __restrict__ W_fc,  const float* __restrict__ b_fc,
    float* __restrict__ out)
{
    __shared__ __attribute__((aligned(16))) short xbf[2*PLX];    // 43008 B
    __shared__ __attribute__((aligned(16))) short h1bf[2*PLH1];  //  6912 B
    __shared__ __attribute__((aligned(16))) short h2bf[2*PLH2];  //  3840 B
    __shared__ __attribute__((aligned(16))) float gpre[3072];    // 12288 B (waves 0-11 regions; also FC stash)
    // Occupancy pad: total LDS > 80KB forces 1 WG/CU -> allocator budgets for
    // 3 waves/EU (~170 regs) instead of 6+ (64-84, spills). [R6/R9/R12 model]
    __shared__ float occ_pad[4672];                              // 18688 B -> ~84.7 KB total

    const int tid  = threadIdx.x;
    const int b0   = blockIdx.x * 8;
    const int w    = tid >> 6;       // wave 0..11
    const int lane = tid & 63;
    const int r    = lane & 15;
    const int g4   = lane >> 4;
    const int up   = lane & 7;            // owned unit within wave's 8
    const int bq   = lane >> 3;           // owned batch 0..7
    const int u1g  = w*8 + up;            // owned L1 unit (waves 0-7)
    const int u2i  = (w & 3)*8 + up;      // owned L2 unit (waves 8-11)
    const f32x4 zero4 = {0.f, 0.f, 0.f, 0.f};

    if (tid == 0) *(volatile float*)occ_pad = 0.f;   // keep pad allocated

    // per-wave pre-act region (256 floats each, w=0..11 -> gpre[0..3071])
    float* gw0 = gpre + ((w*2 + 0)*16 + r)*8;
    float* gw1 = gpre + ((w*2 + 1)*16 + r)*8;
    const float* gp = gpre + (w*32 + up)*8 + bq;   // i/f/g/o at +0,+64,+128,+192

    // zero LDS (pads must be 0: MFMA reads k<160; h rows 16-23 are M-pad)
    for (int i = tid; i < 2*PLX/2;  i += NTHR) ((int*)xbf)[i]  = 0;
    for (int i = tid; i < 2*PLH1/2; i += NTHR) ((int*)h1bf)[i] = 0;
    for (int i = tid; i < 2*PLH2/2; i += NTHR) ((int*)h2bf)[i] = 0;

    float c1 = 0.0f, c2 = 0.0f, h2last = 0.0f;

    __syncthreads();   // zero-init complete before any other xbf write (R8 race fix)

    // bias column k=131 = 1.0 (hi plane only), both buffers (disjoint shorts
    // from the k<131 prologue staging -> race-free in this interval)
    if (tid < 64) {
        int bf_ = tid >> 5, m = tid & 31;
        xbf[bf_*PLX + m*168 + 131] = (short)0x3f80;
    }
    // prologue: stage window 0 into buf 0 (all 768 threads)
    for (int i = tid; i < 4192; i += NTHR) {
        int rn = i / 524; int rem = i - rn*524;
        int tr = rem / 131; int k = rem - tr*131;
        float v = x[(size_t)(b0 + rn)*33536 + tr*131 + k];
        int mrow = tr*8 + rn;
        unsigned short hh = bfrne(v);
        xbf[mrow*168 + k]      = (short)hh;
        xbf[(32+mrow)*168 + k] = (short)bfrne(v - bf2f(hh));
    }
    __syncthreads();

    // ======== wave-specialized pipelined main loop (R12 structure) ========
    if (w < 8) {
        // ---- L1 branch: stationary hi weights; wlo streamed from L2 per window ----
        s16x8 wbf[5][2];      // in-proj W hi   [kt][nt]  (stationary, 40 regs)
        s16x8 whf[2][2][2];   // W_hh1 hi/lo    [nt][kt][sp] (stationary, 32 regs)
        #pragma unroll
        for (int kt = 0; kt < 5; ++kt)
          #pragma unroll
          for (int nt = 0; nt < 2; ++nt)
            wbf[kt][nt] = *(const s16x8*)(wsS + (w*32 + nt*16 + r)*160 + kt*32 + g4*8);
        #pragma unroll
        for (int nt = 0; nt < 2; ++nt)
          #pragma unroll
          for (int kt = 0; kt < 2; ++kt)
            #pragma unroll
            for (int sp = 0; sp < 2; ++sp)
              whf[nt][kt][sp] = *(const s16x8*)(wsS + WS_WHH1 + sp*16384 +
                                                (w*32 + nt*16 + r)*64 + kt*32 + g4*8);
        const short* wloB = wsS + WS_WIH1_LO + (w*32 + r)*160 + g4*8;
        f32x4 accw[2][2];

        for (int w0 = 0; w0 < 64; ++w0) {
            const short* xc = xbf + (w0 & 1)*PLX;
            // in-proj window GEMM: 12 PARALLEL 5-deep chains (term-split acc
            // sets a/b/c), merged once per window. (Was 4x 15-deep.)
            f32x4 acc_b[2][2], acc_c[2][2];
            #pragma unroll
            for (int u = 0; u < 2; ++u)
              #pragma unroll
              for (int nt = 0; nt < 2; ++nt) {
                accw[u][nt] = zero4; acc_b[u][nt] = zero4; acc_c[u][nt] = zero4;
              }
            #pragma unroll
            for (int kt = 0; kt < 5; ++kt) {
              s16x8 wl0 = *(const s16x8*)(wloB + kt*32);           // L2-hot stream
              s16x8 wl1 = *(const s16x8*)(wloB + 16*160 + kt*32);
              #pragma unroll
              for (int u = 0; u < 2; ++u) {
                s16x8 xh = *(const s16x8*)&xc[(u*16 + r)*168 + kt*32 + g4*8];
                s16x8 xl = *(const s16x8*)&xc[(32 + u*16 + r)*168 + kt*32 + g4*8];
                accw[u][0]  = MFMA_B16(xh, wbf[kt][0], accw[u][0]);
                accw[u][1]  = MFMA_B16(xh, wbf[kt][1], accw[u][1]);
                acc_b[u][0] = MFMA_B16(xl, wbf[kt][0], acc_b[u][0]);
                acc_b[u][1] = MFMA_B16(xl, wbf[kt][1], acc_b[u][1]);
                acc_c[u][0] = MFMA_B16(xh, wl0, acc_c[u][0]);
                acc_c[u][1] = MFMA_B16(xh, wl1, acc_c[u][1]);
              }
            }
            #pragma unroll
            for (int u = 0; u < 2; ++u)
              #pragma unroll
              for (int nt = 0; nt < 2; ++nt)
                accw[u][nt] = accw[u][nt] + acc_b[u][nt] + acc_c[u][nt];

            PHASE1(0, 0);  __syncthreads();
            PHASE1(0, 1);  __syncthreads();
            PHASE1(1, 0);  __syncthreads();
            PHASE1(1, 1);  __syncthreads();
        }
        __syncthreads();   // interval 256: L2 finishes step 255
    } else {
        // ---- L2 branch: stationary weights (N=32 slice) + stager state ----
        s16x8 w2f[2][3][2];   // L2 W hi/lo [nt][kt][sp] (kt2 = h2 block)
        #pragma unroll
        for (int nt = 0; nt < 2; ++nt)
          #pragma unroll
          for (int kt = 0; kt < 3; ++kt)
            #pragma unroll
            for (int sp = 0; sp < 2; ++sp)
              w2f[nt][kt][sp] = *(const s16x8*)(wsS + WS_W2 + sp*12288 +
                                                ((w & 3)*32 + nt*16 + r)*96 + kt*32 + g4*8);
        const float l2bi = b_ih2[u2i]      + b_hh2[u2i];
        const float l2bf = b_ih2[32 + u2i] + b_hh2[32 + u2i];
        const float l2bg = b_ih2[64 + u2i] + b_hh2[64 + u2i];
        const float l2bo = b_ih2[96 + u2i] + b_hh2[96 + u2i];

        const int t2 = tid & 255;
        const bool sv4 = (t2 < 24);
        int runm[5], km[5], offm[5];
        #pragma unroll
        for (int m = 0; m < 5; ++m) {
            int j = t2 + 256*m;
            int rn = j / 131;
            runm[m] = rn; km[m] = j - rn*131;
            offm[m] = (b0 + rn)*33536 + km[m];
        }
        float xr[5];
        #pragma unroll
        for (int m = 0; m < 5; ++m)    // prefetch chunk 0 of window 1
            xr[m] = (m < 4 || sv4) ? x[(size_t)(offm[m] + 4*131)] : 0.f;

        for (int w0 = 0; w0 < 64; ++w0) {
            short* xn = xbf + ((w0 & 1) ^ 1)*PLX;
            // steps handled here: 4*w0-1 .. 4*w0+2 (one behind L1)
            STAGE(0);  if (w0 > 0) PHASE2(1);  __syncthreads();
            STAGE(1);  PHASE2(0);              __syncthreads();
            STAGE(2);  PHASE2(1);              __syncthreads();
            STAGE(3);  PHASE2(0);              __syncthreads();
        }
        PHASE2(1);         // step 255
        __syncthreads();   // interval 256
    }

    // ---- FC head (reuse gpre[0..255] as f32 stash of final h2) ----
    if (w >= 8) gpre[bq*32 + u2i] = h2last;
    __syncthreads();
    if (tid < 32) {
        int b = tid >> 2, cls = tid & 3;
        float s = b_fc[cls];
        #pragma unroll
        for (int k2 = 0; k2 < 32; ++k2) s += gpre[b*32 + k2] * W_fc[cls*32 + k2];
        out[(size_t)(b0 + b)*4 + cls] = s;
    }
}

extern "C" void kernel_launch(void* const* d_in, const int* in_sizes, int n_in,
                              void* d_out, int out_size, void* d_ws, size_t ws_size,
                              hipStream_t stream) {
    const float* x     = (const float*)d_in[0];
    const float* W_ih1 = (const float*)d_in[1];
    const float* W_hh1 = (const float*)d_in[2];
    const float* b_ih1 = (const float*)d_in[3];
    const float* b_hh1 = (const float*)d_in[4];
    const float* W_ih2 = (const float*)d_in[5];
    const float* W_hh2 = (const float*)d_in[6];
    const float* b_ih2 = (const float*)d_in[7];
    const float* b_hh2 = (const float*)d_in[8];
    const float* W_fc  = (const float*)d_in[9];
    const float* b_fc  = (const float*)d_in[10];
    float* out = (float*)d_out;
    short* wsS = (short*)d_ws;   // needs 278,528 bytes

    prep_w<<<(PREP_N + 255)/256, 256, 0, stream>>>(W_ih1, W_hh1, W_ih2, W_hh2,
                                                   b_ih1, b_hh1, wsS);
    lstm_mfma<<<B_TOT/8, NTHR, 0, stream>>>(x, wsS, b_ih2, b_hh2, W_fc, b_fc, out);
}

// Round 15
// 306.213 us; speedup vs baseline: 1.2647x; 1.2647x over previous
//
#include <hip/hip_runtime.h>
#include <math.h>

#define B_TOT 2048
#define T_LEN 256
#define D_IN  131
#define NTHR  768   // 12 waves: 0-7 = layer1, 8-11 = layer2(+1-step lag) + staging

typedef __attribute__((ext_vector_type(8))) short s16x8;
typedef __attribute__((ext_vector_type(4))) float f32x4;

#define MFMA_B16(a,b,c) __builtin_amdgcn_mfma_f32_16x16x32_bf16(a, b, c, 0, 0, 0)

// LDS geometry (shorts)
#define PLX   (2*32*168)   // one x buffer: [plane(hi/lo)][32 rows][168]
#define PLH1  (24*72)      // h1: rows 0-7 hi, 8-15 lo, 16-23 zero
#define PLH2  (24*40)

// ws layout (shorts): wih1 hi/lo [2][256][160] @0 (k=131 col = folded bias);
// whh1 hi/lo @81920 ; w2 hi/lo @114688 (k<64 = W_ih2, k>=64 = W_hh2)
#define WS_WIH1_LO 40960
#define WS_WHH1    81920
#define WS_W2      114688
#define PREP_N     (40960 + 16384 + 12288)

__device__ __forceinline__ float rcp_(float x){ return __builtin_amdgcn_rcpf(x); }
__device__ __forceinline__ float sigmoidf_(float x){ return rcp_(1.0f + __expf(-x)); }
__device__ __forceinline__ float tanhf_(float x){
    float ax = fabsf(x);
    float e  = __expf(-2.0f * ax);
    float t  = (1.0f - e) * rcp_(1.0f + e);
    return copysignf(t, x);
}
__device__ __forceinline__ unsigned short bfrne(float f){
    unsigned u = __float_as_uint(f);
    return (unsigned short)((u + 0x7fffu + ((u>>16)&1u)) >> 16);
}
__device__ __forceinline__ float bf2f(unsigned short h){
    return __uint_as_float(((unsigned)h)<<16);
}

// Column permutation: tile col packs [i-units(8) | f-units(8)] / [g | o] per wave.
__global__ void prep_w(const float* __restrict__ W_ih1, const float* __restrict__ W_hh1,
                       const float* __restrict__ W_ih2, const float* __restrict__ W_hh2,
                       const float* __restrict__ b_ih1, const float* __restrict__ b_hh1,
                       short* __restrict__ wsS) {
    int i = blockIdx.x*256 + threadIdx.x;
    if (i >= PREP_N) return;
    if (i < 40960) {                       // W_ih1 hi/lo: [n'][160], k=131 -> bias
        int np = i / 160, k = i - np*160;
        int u = (np>>5)*8 + (np&7);
        int gate = ((np>>4)&1)*2 + ((np>>3)&1);
        int n = gate*64 + u;
        float v;
        if (k < D_IN)       v = W_ih1[n*D_IN + k];
        else if (k == D_IN) v = b_ih1[n] + b_hh1[n];
        else                v = 0.0f;
        unsigned short hi = bfrne(v);
        wsS[i]              = (short)hi;
        wsS[WS_WIH1_LO + i] = (short)bfrne(v - bf2f(hi));
    } else if (i < 40960 + 16384) {        // W_hh1 hi/lo: [n'][64]
        int j = i - 40960;
        int np = j >> 6, k = j & 63;
        int u = (np>>5)*8 + (np&7);
        int gate = ((np>>4)&1)*2 + ((np>>3)&1);
        int n = gate*64 + u;
        float v = W_hh1[n*64 + k];
        unsigned short hi = bfrne(v);
        wsS[WS_WHH1 + j]         = (short)hi;
        wsS[WS_WHH1 + 16384 + j] = (short)bfrne(v - bf2f(hi));
    } else {                               // W_ih2|W_hh2 hi/lo: [n'][96]
        int j = i - (40960 + 16384);
        int np = j / 96, k = j - np*96;
        int u = ((np>>5)&3)*8 + (np&7);
        int gate = ((np>>4)&1)*2 + ((np>>3)&1);
        int n = gate*32 + u;
        float v = (k < 64) ? W_ih2[n*64 + k] : W_hh2[n*32 + (k - 64)];
        unsigned short hi = bfrne(v);
        wsS[WS_W2 + j]         = (short)hi;
        wsS[WS_W2 + 12288 + j] = (short)bfrne(v - bf2f(hi));
    }
}

// ---- PHASE1 (waves 0-7): layer-1, N=32 cols/wave. Rec = 4 PARALLEL 3-deep
// chains: accw[U][0/1] take half, transient rE/sE take half (+8 regs only);
// rE/sE's nonzero rows are exactly this parity's rows (zero-A-row property),
// so adding them at scatter is exact and accw keeps its parity-row residue.
#define PHASE1(U, P) do { \
  const short* h1r = h1bf + (P)*PLH1; \
  short*       h1w = h1bf + (1-(P))*PLH1; \
  const int rH = (r & 7) + 16*(((r >> 3) ^ (P)) & 1); \
  const int rL = 8 + (r & 7) + 8*(((r >> 3) ^ (P)) & 1); \
  s16x8 ah0 = *(const s16x8*)&h1r[rH*72 + g4*8]; \
  s16x8 ah1 = *(const s16x8*)&h1r[rH*72 + 32 + g4*8]; \
  s16x8 al0 = *(const s16x8*)&h1r[rL*72 + g4*8]; \
  s16x8 al1 = *(const s16x8*)&h1r[rL*72 + 32 + g4*8]; \
  f32x4 rE = zero4, sE = zero4; \
  accw[U][0] = MFMA_B16(ah0, whf[0][0][0], accw[U][0]); \
  accw[U][1] = MFMA_B16(ah0, whf[1][0][0], accw[U][1]); \
  rE = MFMA_B16(ah0, whf[0][0][1], rE); \
  sE = MFMA_B16(ah0, whf[1][0][1], sE); \
  accw[U][0] = MFMA_B16(ah1, whf[0][1][0], accw[U][0]); \
  accw[U][1] = MFMA_B16(ah1, whf[1][1][0], accw[U][1]); \
  rE = MFMA_B16(ah1, whf[0][1][1], rE); \
  sE = MFMA_B16(ah1, whf[1][1][1], sE); \
  accw[U][0] = MFMA_B16(al0, whf[0][0][0], accw[U][0]); \
  accw[U][1] = MFMA_B16(al0, whf[1][0][0], accw[U][1]); \
  rE = MFMA_B16(al1, whf[0][1][0], rE); \
  sE = MFMA_B16(al1, whf[1][1][0], sE); \
  if ((g4 >> 1) == (P)) { \
    *(f32x4*)(gw0 + 4*(g4 & 1)) = accw[U][0] + rE; \
    *(f32x4*)(gw1 + 4*(g4 & 1)) = accw[U][1] + sE; \
  } \
  float gi = sigmoidf_(gp[0]);     /* bias folded via k=131 column */ \
  float gf = sigmoidf_(gp[64]); \
  float gg = tanhf_   (gp[128]); \
  float go = sigmoidf_(gp[192]); \
  c1 = gf * c1 + gi * gg; \
  float hv = go * tanhf_(c1); \
  unsigned short hh = bfrne(hv); \
  h1w[bq*72 + u1g]     = (short)hh; \
  h1w[(8+bq)*72 + u1g] = (short)bfrne(hv - bf2f(hh)); \
} while(0)

// ---- PHASE2 (waves 8-11): layer-2 one step behind; 4 PARALLEL chains
// (5,5,4,4-deep; was 2x9-deep). +8 regs only on the L2 branch, which is
// below the L1 branch's register max -> free.
#define PHASE2(P) do { \
  const short* h1n = h1bf + (1-(P))*PLH1; \
  const short* h2r = h2bf + (P)*PLH2; \
  short*       h2w = h2bf + (1-(P))*PLH2; \
  const int rH2 = (r & 7) + 16*(r >> 3); \
  const int rL2 = 8 + (r & 7) + 8*(r >> 3); \
  s16x8 ah0 = *(const s16x8*)&h1n[rH2*72 + g4*8]; \
  s16x8 ah1 = *(const s16x8*)&h1n[rH2*72 + 32 + g4*8]; \
  s16x8 al0 = *(const s16x8*)&h1n[rL2*72 + g4*8]; \
  s16x8 al1 = *(const s16x8*)&h1n[rL2*72 + 32 + g4*8]; \
  s16x8 bh  = *(const s16x8*)&h2r[rH2*40 + g4*8]; \
  s16x8 bl  = *(const s16x8*)&h2r[rL2*40 + g4*8]; \
  f32x4 p0 = zero4, p1 = zero4, pE = zero4, qE = zero4; \
  p0 = MFMA_B16(ah0, w2f[0][0][0], p0);  p1 = MFMA_B16(ah0, w2f[1][0][0], p1); \
  pE = MFMA_B16(ah0, w2f[0][0][1], pE);  qE = MFMA_B16(ah0, w2f[1][0][1], qE); \
  p0 = MFMA_B16(ah1, w2f[0][1][0], p0);  p1 = MFMA_B16(ah1, w2f[1][1][0], p1); \
  pE = MFMA_B16(ah1, w2f[0][1][1], pE);  qE = MFMA_B16(ah1, w2f[1][1][1], qE); \
  p0 = MFMA_B16(bh,  w2f[0][2][0], p0);  p1 = MFMA_B16(bh,  w2f[1][2][0], p1); \
  pE = MFMA_B16(bh,  w2f[0][2][1], pE);  qE = MFMA_B16(bh,  w2f[1][2][1], qE); \
  p0 = MFMA_B16(al0, w2f[0][0][0], p0);  p1 = MFMA_B16(al0, w2f[1][0][0], p1); \
  pE = MFMA_B16(al1, w2f[0][1][0], pE);  qE = MFMA_B16(al1, w2f[1][1][0], qE); \
  p0 = MFMA_B16(bl,  w2f[0][2][0], p0);  p1 = MFMA_B16(bl,  w2f[1][2][0], p1); \
  if (g4 < 2) { \
    *(f32x4*)(gw0 + 4*g4) = p0 + pE; \
    *(f32x4*)(gw1 + 4*g4) = p1 + qE; \
  } \
  float gi = sigmoidf_(gp[0]   + l2bi); \
  float gf = sigmoidf_(gp[64]  + l2bf); \
  float gg = tanhf_   (gp[128] + l2bg); \
  float go = sigmoidf_(gp[192] + l2bo); \
  c2 = gf * c2 + gi * gg; \
  float hv = go * tanhf_(c2); \
  h2last = hv; \
  unsigned short hh = bfrne(hv); \
  h2w[bq*40 + u2i]     = (short)hh; \
  h2w[(8+bq)*40 + u2i] = (short)bfrne(hv - bf2f(hh)); \
} while(0)

// ---- STAGE (waves 8-11, 256 lanes): write chunk S of next window, prefetch.
#define STAGE(S) do { \
  if (w0 < 63) { \
    _Pragma("unroll") \
    for (int m = 0; m < 5; ++m) { \
      if (m < 4 || sv4) { \
        int mrow = (S)*8 + runm[m]; \
        unsigned short hh = bfrne(xr[m]); \
        xn[mrow*168 + km[m]]      = (short)hh; \
        xn[(32+mrow)*168 + km[m]] = (short)bfrne(xr[m] - bf2f(hh)); \
      } \
    } \
    if ((S) < 3 || w0 <= 61) { \
      int tl = ((S) < 3) ? ((w0+1)*4 + (S) + 1) : ((w0+2)*4); \
      _Pragma("unroll") \
      for (int m = 0; m < 5; ++m) \
        if (m < 4 || sv4) xr[m] = x[(size_t)(offm[m] + tl*131)]; \
    } \
  } \
} while(0)

__global__ __launch_bounds__(NTHR, 1) void lstm_mfma(
    const float* __restrict__ x,
    const short* __restrict__ wsS,
    const float* __restrict__ b_ih2, const float* __restrict__ b_hh2,
    const float* __restrict__ W_fc,  const float* __restrict__ b_fc,
    float* __restrict__ out)
{
    __shared__ __attribute__((aligned(16))) short xbf[2*PLX];    // 43008 B
    __shared__ __attribute__((aligned(16))) short h1bf[2*PLH1];  //  6912 B
    __shared__ __attribute__((aligned(16))) short h2bf[2*PLH2];  //  3840 B
    __shared__ __attribute__((aligned(16))) float gpre[3072];    // 12288 B (waves 0-11 regions; also FC stash)
    // Occupancy pad: total LDS > 80KB forces 1 WG/CU -> allocator budgets for
    // 3 waves/EU instead of 6+ (would spill). [R6/R9/R12 evidence]
    __shared__ float occ_pad[4672];                              // 18688 B -> ~84.7 KB total

    const int tid  = threadIdx.x;
    const int b0   = blockIdx.x * 8;
    const int w    = tid >> 6;       // wave 0..11
    const int lane = tid & 63;
    const int r    = lane & 15;
    const int g4   = lane >> 4;
    const int up   = lane & 7;            // owned unit within wave's 8
    const int bq   = lane >> 3;           // owned batch 0..7
    const int u1g  = w*8 + up;            // owned L1 unit (waves 0-7)
    const int u2i  = (w & 3)*8 + up;      // owned L2 unit (waves 8-11)
    const f32x4 zero4 = {0.f, 0.f, 0.f, 0.f};

    if (tid == 0) *(volatile float*)occ_pad = 0.f;   // keep pad allocated

    // per-wave pre-act region (256 floats each, w=0..11 -> gpre[0..3071])
    float* gw0 = gpre + ((w*2 + 0)*16 + r)*8;
    float* gw1 = gpre + ((w*2 + 1)*16 + r)*8;
    const float* gp = gpre + (w*32 + up)*8 + bq;   // i/f/g/o at +0,+64,+128,+192

    // zero LDS (pads must be 0: MFMA reads k<160; h rows 16-23 are M-pad)
    for (int i = tid; i < 2*PLX/2;  i += NTHR) ((int*)xbf)[i]  = 0;
    for (int i = tid; i < 2*PLH1/2; i += NTHR) ((int*)h1bf)[i] = 0;
    for (int i = tid; i < 2*PLH2/2; i += NTHR) ((int*)h2bf)[i] = 0;

    float c1 = 0.0f, c2 = 0.0f, h2last = 0.0f;

    __syncthreads();   // zero-init complete before any other xbf write (R8 race fix)

    // bias column k=131 = 1.0 (hi plane only), both buffers (disjoint shorts
    // from the k<131 prologue staging -> race-free in this interval)
    if (tid < 64) {
        int bf_ = tid >> 5, m = tid & 31;
        xbf[bf_*PLX + m*168 + 131] = (short)0x3f80;
    }
    // prologue: stage window 0 into buf 0 (all 768 threads)
    for (int i = tid; i < 4192; i += NTHR) {
        int rn = i / 524; int rem = i - rn*524;
        int tr = rem / 131; int k = rem - tr*131;
        float v = x[(size_t)(b0 + rn)*33536 + tr*131 + k];
        int mrow = tr*8 + rn;
        unsigned short hh = bfrne(v);
        xbf[mrow*168 + k]      = (short)hh;
        xbf[(32+mrow)*168 + k] = (short)bfrne(v - bf2f(hh));
    }
    __syncthreads();

    // ======== wave-specialized pipelined main loop (R12 structure) ========
    if (w < 8) {
        // ---- L1 branch: ALL weights stationary (R13's wlo streaming cost
        // +40MB HBM fetch/dispatch -- reverted) ----
        s16x8 wbf[5][2];      // in-proj W hi   [kt][nt]
        s16x8 wlo[5][2];      // in-proj W lo   [kt][nt]
        s16x8 whf[2][2][2];   // W_hh1 hi/lo    [nt][kt][sp]
        #pragma unroll
        for (int kt = 0; kt < 5; ++kt)
          #pragma unroll
          for (int nt = 0; nt < 2; ++nt) {
            wbf[kt][nt] = *(const s16x8*)(wsS + (w*32 + nt*16 + r)*160 + kt*32 + g4*8);
            wlo[kt][nt] = *(const s16x8*)(wsS + WS_WIH1_LO + (w*32 + nt*16 + r)*160 + kt*32 + g4*8);
          }
        #pragma unroll
        for (int nt = 0; nt < 2; ++nt)
          #pragma unroll
          for (int kt = 0; kt < 2; ++kt)
            #pragma unroll
            for (int sp = 0; sp < 2; ++sp)
              whf[nt][kt][sp] = *(const s16x8*)(wsS + WS_WHH1 + sp*16384 +
                                                (w*32 + nt*16 + r)*64 + kt*32 + g4*8);
        f32x4 accw[2][2];

        for (int w0 = 0; w0 < 64; ++w0) {
            const short* xc = xbf + (w0 & 1)*PLX;
            // in-proj window GEMM (R12 form): M=32, N=32/wave, K=160, 3 terms
            #pragma unroll
            for (int u = 0; u < 2; ++u)
              #pragma unroll
              for (int nt = 0; nt < 2; ++nt) accw[u][nt] = zero4;
            #pragma unroll
            for (int kt = 0; kt < 5; ++kt) {
              #pragma unroll
              for (int u = 0; u < 2; ++u) {
                s16x8 xh = *(const s16x8*)&xc[(u*16 + r)*168 + kt*32 + g4*8];
                s16x8 xl = *(const s16x8*)&xc[(32 + u*16 + r)*168 + kt*32 + g4*8];
                accw[u][0] = MFMA_B16(xh, wbf[kt][0], accw[u][0]);
                accw[u][1] = MFMA_B16(xh, wbf[kt][1], accw[u][1]);
                accw[u][0] = MFMA_B16(xl, wbf[kt][0], accw[u][0]);
                accw[u][1] = MFMA_B16(xl, wbf[kt][1], accw[u][1]);
                accw[u][0] = MFMA_B16(xh, wlo[kt][0], accw[u][0]);
                accw[u][1] = MFMA_B16(xh, wlo[kt][1], accw[u][1]);
              }
            }
            PHASE1(0, 0);  __syncthreads();
            PHASE1(0, 1);  __syncthreads();
            PHASE1(1, 0);  __syncthreads();
            PHASE1(1, 1);  __syncthreads();
        }
        __syncthreads();   // interval 256: L2 finishes step 255
    } else {
        // ---- L2 branch: stationary weights (N=32 slice) + stager state ----
        s16x8 w2f[2][3][2];   // L2 W hi/lo [nt][kt][sp] (kt2 = h2 block)
        #pragma unroll
        for (int nt = 0; nt < 2; ++nt)
          #pragma unroll
          for (int kt = 0; kt < 3; ++kt)
            #pragma unroll
            for (int sp = 0; sp < 2; ++sp)
              w2f[nt][kt][sp] = *(const s16x8*)(wsS + WS_W2 + sp*12288 +
                                                ((w & 3)*32 + nt*16 + r)*96 + kt*32 + g4*8);
        const float l2bi = b_ih2[u2i]      + b_hh2[u2i];
        const float l2bf = b_ih2[32 + u2i] + b_hh2[32 + u2i];
        const float l2bg = b_ih2[64 + u2i] + b_hh2[64 + u2i];
        const float l2bo = b_ih2[96 + u2i] + b_hh2[96 + u2i];

        const int t2 = tid & 255;
        const bool sv4 = (t2 < 24);
        int runm[5], km[5], offm[5];
        #pragma unroll
        for (int m = 0; m < 5; ++m) {
            int j = t2 + 256*m;
            int rn = j / 131;
            runm[m] = rn; km[m] = j - rn*131;
            offm[m] = (b0 + rn)*33536 + km[m];
        }
        float xr[5];
        #pragma unroll
        for (int m = 0; m < 5; ++m)    // prefetch chunk 0 of window 1
            xr[m] = (m < 4 || sv4) ? x[(size_t)(offm[m] + 4*131)] : 0.f;

        for (int w0 = 0; w0 < 64; ++w0) {
            short* xn = xbf + ((w0 & 1) ^ 1)*PLX;
            // steps handled here: 4*w0-1 .. 4*w0+2 (one behind L1)
            STAGE(0);  if (w0 > 0) PHASE2(1);  __syncthreads();
            STAGE(1);  PHASE2(0);              __syncthreads();
            STAGE(2);  PHASE2(1);              __syncthreads();
            STAGE(3);  PHASE2(0);              __syncthreads();
        }
        PHASE2(1);         // step 255
        __syncthreads();   // interval 256
    }

    // ---- FC head (reuse gpre[0..255] as f32 stash of final h2) ----
    if (w >= 8) gpre[bq*32 + u2i] = h2last;
    __syncthreads();
    if (tid < 32) {
        int b = tid >> 2, cls = tid & 3;
        float s = b_fc[cls];
        #pragma unroll
        for (int k2 = 0; k2 < 32; ++k2) s += gpre[b*32 + k2] * W_fc[cls*32 + k2];
        out[(size_t)(b0 + b)*4 + cls] = s;
    }
}

extern "C" void kernel_launch(void* const* d_in, const int* in_sizes, int n_in,
                              void* d_out, int out_size, void* d_ws, size_t ws_size,
                              hipStream_t stream) {
    const float* x     = (const float*)d_in[0];
    const float* W_ih1 = (const float*)d_in[1];
    const float* W_hh1 = (const float*)d_in[2];
    const float* b_ih1 = (const float*)d_in[3];
    const float* b_hh1 = (const float*)d_in[4];
    const float* W_ih2 = (const float*)d_in[5];
    const float* W_hh2 = (const float*)d_in[6];
    const float* b_ih2 = (const float*)d_in[7];
    const float* b_hh2 = (const float*)d_in[8];
    const float* W_fc  = (const float*)d_in[9];
    const float* b_fc  = (const float*)d_in[10];
    float* out = (float*)d_out;
    short* wsS = (short*)d_ws;   // needs 278,528 bytes

    prep_w<<<(PREP_N + 255)/256, 256, 0, stream>>>(W_ih1, W_hh1, W_ih2, W_hh2,
                                                   b_ih1, b_hh1, wsS);
    lstm_mfma<<<B_TOT/8, NTHR, 0, stream>>>(x, wsS, b_ih2, b_hh2, W_fc, b_fc, out);
}

// Round 16
// 286.287 us; speedup vs baseline: 1.3527x; 1.0696x over previous
//
#include <hip/hip_runtime.h>
#include <math.h>

#define B_TOT 2048
#define T_LEN 256
#define D_IN  131
#define NTHR  768   // 12 waves: 0-7 = layer1, 8-11 = layer2(+1-step lag) + staging

typedef __attribute__((ext_vector_type(8))) short s16x8;
typedef __attribute__((ext_vector_type(4))) float f32x4;

#define MFMA_B16(a,b,c) __builtin_amdgcn_mfma_f32_16x16x32_bf16(a, b, c, 0, 0, 0)

// Hot-loop barrier: LDS-drain + raw s_barrier. __syncthreads() would emit
// s_waitcnt vmcnt(0) lgkmcnt(0) -- draining the stager's in-flight x loads
// (~500-900cy HBM/L3) at EVERY step barrier. The x loads are consumed only
// by the issuing wave in registers, so only LDS needs cross-wave visibility.
#define BAR() do { \
  asm volatile("s_waitcnt lgkmcnt(0)" ::: "memory"); \
  __builtin_amdgcn_s_barrier(); \
} while(0)

// LDS geometry (shorts)
#define PLX   (2*32*168)   // one x buffer: [plane(hi/lo)][32 rows][168]
#define PLH1  (24*72)      // h1: rows 0-7 hi, 8-15 lo, 16-23 zero
#define PLH2  (24*40)

// ws layout (shorts): wih1 hi/lo [2][256][160] @0 (k=131 col = folded bias);
// whh1 hi/lo @81920 ; w2 hi/lo @114688 (k<64 = W_ih2, k>=64 = W_hh2)
#define WS_WIH1_LO 40960
#define WS_WHH1    81920
#define WS_W2      114688
#define PREP_N     (40960 + 16384 + 12288)

__device__ __forceinline__ float rcp_(float x){ return __builtin_amdgcn_rcpf(x); }
__device__ __forceinline__ float sigmoidf_(float x){ return rcp_(1.0f + __expf(-x)); }
__device__ __forceinline__ float tanhf_(float x){
    float ax = fabsf(x);
    float e  = __expf(-2.0f * ax);
    float t  = (1.0f - e) * rcp_(1.0f + e);
    return copysignf(t, x);
}
__device__ __forceinline__ unsigned short bfrne(float f){
    unsigned u = __float_as_uint(f);
    return (unsigned short)((u + 0x7fffu + ((u>>16)&1u)) >> 16);
}
__device__ __forceinline__ float bf2f(unsigned short h){
    return __uint_as_float(((unsigned)h)<<16);
}

// Column permutation: tile col packs [i-units(8) | f-units(8)] / [g | o] per wave.
__global__ void prep_w(const float* __restrict__ W_ih1, const float* __restrict__ W_hh1,
                       const float* __restrict__ W_ih2, const float* __restrict__ W_hh2,
                       const float* __restrict__ b_ih1, const float* __restrict__ b_hh1,
                       short* __restrict__ wsS) {
    int i = blockIdx.x*256 + threadIdx.x;
    if (i >= PREP_N) return;
    if (i < 40960) {                       // W_ih1 hi/lo: [n'][160], k=131 -> bias
        int np = i / 160, k = i - np*160;
        int u = (np>>5)*8 + (np&7);
        int gate = ((np>>4)&1)*2 + ((np>>3)&1);
        int n = gate*64 + u;
        float v;
        if (k < D_IN)       v = W_ih1[n*D_IN + k];
        else if (k == D_IN) v = b_ih1[n] + b_hh1[n];
        else                v = 0.0f;
        unsigned short hi = bfrne(v);
        wsS[i]              = (short)hi;
        wsS[WS_WIH1_LO + i] = (short)bfrne(v - bf2f(hi));
    } else if (i < 40960 + 16384) {        // W_hh1 hi/lo: [n'][64]
        int j = i - 40960;
        int np = j >> 6, k = j & 63;
        int u = (np>>5)*8 + (np&7);
        int gate = ((np>>4)&1)*2 + ((np>>3)&1);
        int n = gate*64 + u;
        float v = W_hh1[n*64 + k];
        unsigned short hi = bfrne(v);
        wsS[WS_WHH1 + j]         = (short)hi;
        wsS[WS_WHH1 + 16384 + j] = (short)bfrne(v - bf2f(hi));
    } else {                               // W_ih2|W_hh2 hi/lo: [n'][96]
        int j = i - (40960 + 16384);
        int np = j / 96, k = j - np*96;
        int u = ((np>>5)&3)*8 + (np&7);
        int gate = ((np>>4)&1)*2 + ((np>>3)&1);
        int n = gate*32 + u;
        float v = (k < 64) ? W_ih2[n*64 + k] : W_hh2[n*32 + (k - 64)];
        unsigned short hi = bfrne(v);
        wsS[WS_W2 + j]         = (short)hi;
        wsS[WS_W2 + 12288 + j] = (short)bfrne(v - bf2f(hi));
    }
}

// ---- PHASE1 (waves 0-7): layer-1, N=32 cols/wave. Rec = 4 parallel 3-deep
// chains (R15 form). Scatter pre-acts to per-wave gpre region, gather own
// cell (same-wave LDS write->read).
#define PHASE1(U, P) do { \
  const short* h1r = h1bf + (P)*PLH1; \
  short*       h1w = h1bf + (1-(P))*PLH1; \
  const int rH = (r & 7) + 16*(((r >> 3) ^ (P)) & 1); \
  const int rL = 8 + (r & 7) + 8*(((r >> 3) ^ (P)) & 1); \
  s16x8 ah0 = *(const s16x8*)&h1r[rH*72 + g4*8]; \
  s16x8 ah1 = *(const s16x8*)&h1r[rH*72 + 32 + g4*8]; \
  s16x8 al0 = *(const s16x8*)&h1r[rL*72 + g4*8]; \
  s16x8 al1 = *(const s16x8*)&h1r[rL*72 + 32 + g4*8]; \
  f32x4 rE = zero4, sE = zero4; \
  accw[U][0] = MFMA_B16(ah0, whf[0][0][0], accw[U][0]); \
  accw[U][1] = MFMA_B16(ah0, whf[1][0][0], accw[U][1]); \
  rE = MFMA_B16(ah0, whf[0][0][1], rE); \
  sE = MFMA_B16(ah0, whf[1][0][1], sE); \
  accw[U][0] = MFMA_B16(ah1, whf[0][1][0], accw[U][0]); \
  accw[U][1] = MFMA_B16(ah1, whf[1][1][0], accw[U][1]); \
  rE = MFMA_B16(ah1, whf[0][1][1], rE); \
  sE = MFMA_B16(ah1, whf[1][1][1], sE); \
  accw[U][0] = MFMA_B16(al0, whf[0][0][0], accw[U][0]); \
  accw[U][1] = MFMA_B16(al0, whf[1][0][0], accw[U][1]); \
  rE = MFMA_B16(al1, whf[0][1][0], rE); \
  sE = MFMA_B16(al1, whf[1][1][0], sE); \
  if ((g4 >> 1) == (P)) { \
    *(f32x4*)(gw0 + 4*(g4 & 1)) = accw[U][0] + rE; \
    *(f32x4*)(gw1 + 4*(g4 & 1)) = accw[U][1] + sE; \
  } \
  float gi = sigmoidf_(gp[0]);     /* bias folded via k=131 column */ \
  float gf = sigmoidf_(gp[64]); \
  float gg = tanhf_   (gp[128]); \
  float go = sigmoidf_(gp[192]); \
  c1 = gf * c1 + gi * gg; \
  float hv = go * tanhf_(c1); \
  unsigned short hh = bfrne(hv); \
  h1w[bq*72 + u1g]     = (short)hh; \
  h1w[(8+bq)*72 + u1g] = (short)bfrne(hv - bf2f(hh)); \
} while(0)

// ---- PHASE2 (waves 8-11): layer-2 one step behind; 4 parallel chains.
#define PHASE2(P) do { \
  const short* h1n = h1bf + (1-(P))*PLH1; \
  const short* h2r = h2bf + (P)*PLH2; \
  short*       h2w = h2bf + (1-(P))*PLH2; \
  const int rH2 = (r & 7) + 16*(r >> 3); \
  const int rL2 = 8 + (r & 7) + 8*(r >> 3); \
  s16x8 ah0 = *(const s16x8*)&h1n[rH2*72 + g4*8]; \
  s16x8 ah1 = *(const s16x8*)&h1n[rH2*72 + 32 + g4*8]; \
  s16x8 al0 = *(const s16x8*)&h1n[rL2*72 + g4*8]; \
  s16x8 al1 = *(const s16x8*)&h1n[rL2*72 + 32 + g4*8]; \
  s16x8 bh  = *(const s16x8*)&h2r[rH2*40 + g4*8]; \
  s16x8 bl  = *(const s16x8*)&h2r[rL2*40 + g4*8]; \
  f32x4 p0 = zero4, p1 = zero4, pE = zero4, qE = zero4; \
  p0 = MFMA_B16(ah0, w2f[0][0][0], p0);  p1 = MFMA_B16(ah0, w2f[1][0][0], p1); \
  pE = MFMA_B16(ah0, w2f[0][0][1], pE);  qE = MFMA_B16(ah0, w2f[1][0][1], qE); \
  p0 = MFMA_B16(ah1, w2f[0][1][0], p0);  p1 = MFMA_B16(ah1, w2f[1][1][0], p1); \
  pE = MFMA_B16(ah1, w2f[0][1][1], pE);  qE = MFMA_B16(ah1, w2f[1][1][1], qE); \
  p0 = MFMA_B16(bh,  w2f[0][2][0], p0);  p1 = MFMA_B16(bh,  w2f[1][2][0], p1); \
  pE = MFMA_B16(bh,  w2f[0][2][1], pE);  qE = MFMA_B16(bh,  w2f[1][2][1], qE); \
  p0 = MFMA_B16(al0, w2f[0][0][0], p0);  p1 = MFMA_B16(al0, w2f[1][0][0], p1); \
  pE = MFMA_B16(al1, w2f[0][1][0], pE);  qE = MFMA_B16(al1, w2f[1][1][0], qE); \
  p0 = MFMA_B16(bl,  w2f[0][2][0], p0);  p1 = MFMA_B16(bl,  w2f[1][2][0], p1); \
  if (g4 < 2) { \
    *(f32x4*)(gw0 + 4*g4) = p0 + pE; \
    *(f32x4*)(gw1 + 4*g4) = p1 + qE; \
  } \
  float gi = sigmoidf_(gp[0]   + l2bi); \
  float gf = sigmoidf_(gp[64]  + l2bf); \
  float gg = tanhf_   (gp[128] + l2bg); \
  float go = sigmoidf_(gp[192] + l2bo); \
  c2 = gf * c2 + gi * gg; \
  float hv = go * tanhf_(c2); \
  h2last = hv; \
  unsigned short hh = bfrne(hv); \
  h2w[bq*40 + u2i]     = (short)hh; \
  h2w[(8+bq)*40 + u2i] = (short)bfrne(hv - bf2f(hh)); \
} while(0)

// ---- STAGE (waves 8-11, 256 lanes): write chunk S of next window, prefetch.
// With BAR(), the prefetch loads issued here stay in flight ACROSS barriers.
#define STAGE(S) do { \
  if (w0 < 63) { \
    _Pragma("unroll") \
    for (int m = 0; m < 5; ++m) { \
      if (m < 4 || sv4) { \
        int mrow = (S)*8 + runm[m]; \
        unsigned short hh = bfrne(xr[m]); \
        xn[mrow*168 + km[m]]      = (short)hh; \
        xn[(32+mrow)*168 + km[m]] = (short)bfrne(xr[m] - bf2f(hh)); \
      } \
    } \
    if ((S) < 3 || w0 <= 61) { \
      int tl = ((S) < 3) ? ((w0+1)*4 + (S) + 1) : ((w0+2)*4); \
      _Pragma("unroll") \
      for (int m = 0; m < 5; ++m) \
        if (m < 4 || sv4) xr[m] = x[(size_t)(offm[m] + tl*131)]; \
    } \
  } \
} while(0)

__global__ __launch_bounds__(NTHR, 1) void lstm_mfma(
    const float* __restrict__ x,
    const short* __restrict__ wsS,
    const float* __restrict__ b_ih2, const float* __restrict__ b_hh2,
    const float* __restrict__ W_fc,  const float* __restrict__ b_fc,
    float* __restrict__ out)
{
    __shared__ __attribute__((aligned(16))) short xbf[2*PLX];    // 43008 B
    __shared__ __attribute__((aligned(16))) short h1bf[2*PLH1];  //  6912 B
    __shared__ __attribute__((aligned(16))) short h2bf[2*PLH2];  //  3840 B
    __shared__ __attribute__((aligned(16))) float gpre[3072];    // 12288 B (waves 0-11 regions; also FC stash)
    // Occupancy pad: total LDS > 80KB forces 1 WG/CU -> allocator budgets for
    // 3 waves/EU instead of 6+ (would spill). [R6/R9/R12 evidence]
    __shared__ float occ_pad[4672];                              // 18688 B -> ~84.7 KB total

    const int tid  = threadIdx.x;
    const int b0   = blockIdx.x * 8;
    const int w    = tid >> 6;       // wave 0..11
    const int lane = tid & 63;
    const int r    = lane & 15;
    const int g4   = lane >> 4;
    const int up   = lane & 7;            // owned unit within wave's 8
    const int bq   = lane >> 3;           // owned batch 0..7
    const int u1g  = w*8 + up;            // owned L1 unit (waves 0-7)
    const int u2i  = (w & 3)*8 + up;      // owned L2 unit (waves 8-11)
    const f32x4 zero4 = {0.f, 0.f, 0.f, 0.f};

    if (tid == 0) *(volatile float*)occ_pad = 0.f;   // keep pad allocated

    // per-wave pre-act region (256 floats each, w=0..11 -> gpre[0..3071])
    float* gw0 = gpre + ((w*2 + 0)*16 + r)*8;
    float* gw1 = gpre + ((w*2 + 1)*16 + r)*8;
    const float* gp = gpre + (w*32 + up)*8 + bq;   // i/f/g/o at +0,+64,+128,+192

    // zero LDS (pads must be 0: MFMA reads k<160; h rows 16-23 are M-pad)
    for (int i = tid; i < 2*PLX/2;  i += NTHR) ((int*)xbf)[i]  = 0;
    for (int i = tid; i < 2*PLH1/2; i += NTHR) ((int*)h1bf)[i] = 0;
    for (int i = tid; i < 2*PLH2/2; i += NTHR) ((int*)h2bf)[i] = 0;

    float c1 = 0.0f, c2 = 0.0f, h2last = 0.0f;

    __syncthreads();   // zero-init complete before any other xbf write (R8 race fix)

    // bias column k=131 = 1.0 (hi plane only), both buffers (disjoint shorts
    // from the k<131 prologue staging -> race-free in this interval)
    if (tid < 64) {
        int bf_ = tid >> 5, m = tid & 31;
        xbf[bf_*PLX + m*168 + 131] = (short)0x3f80;
    }
    // prologue: stage window 0 into buf 0 (all 768 threads)
    for (int i = tid; i < 4192; i += NTHR) {
        int rn = i / 524; int rem = i - rn*524;
        int tr = rem / 131; int k = rem - tr*131;
        float v = x[(size_t)(b0 + rn)*33536 + tr*131 + k];
        int mrow = tr*8 + rn;
        unsigned short hh = bfrne(v);
        xbf[mrow*168 + k]      = (short)hh;
        xbf[(32+mrow)*168 + k] = (short)bfrne(v - bf2f(hh));
    }
    __syncthreads();

    // ======== wave-specialized pipelined main loop (R12 structure) ========
    // Hot loop uses BAR(): lgkmcnt(0) + raw s_barrier. Both branches execute
    // exactly 257 BAR()s. Cross-wave communication is ALL through LDS
    // (h1bf/h2bf/xbf/gpre) -> lgkmcnt(0) drain seals it; the stager's global
    // loads live in wave-private registers and legally span barriers.
    if (w < 8) {
        // ---- L1 branch: ALL weights stationary ----
        s16x8 wbf[5][2];      // in-proj W hi   [kt][nt]
        s16x8 wlo[5][2];      // in-proj W lo   [kt][nt]
        s16x8 whf[2][2][2];   // W_hh1 hi/lo    [nt][kt][sp]
        #pragma unroll
        for (int kt = 0; kt < 5; ++kt)
          #pragma unroll
          for (int nt = 0; nt < 2; ++nt) {
            wbf[kt][nt] = *(const s16x8*)(wsS + (w*32 + nt*16 + r)*160 + kt*32 + g4*8);
            wlo[kt][nt] = *(const s16x8*)(wsS + WS_WIH1_LO + (w*32 + nt*16 + r)*160 + kt*32 + g4*8);
          }
        #pragma unroll
        for (int nt = 0; nt < 2; ++nt)
          #pragma unroll
          for (int kt = 0; kt < 2; ++kt)
            #pragma unroll
            for (int sp = 0; sp < 2; ++sp)
              whf[nt][kt][sp] = *(const s16x8*)(wsS + WS_WHH1 + sp*16384 +
                                                (w*32 + nt*16 + r)*64 + kt*32 + g4*8);
        f32x4 accw[2][2];

        for (int w0 = 0; w0 < 64; ++w0) {
            const short* xc = xbf + (w0 & 1)*PLX;
            // in-proj window GEMM: M=32, N=32/wave, K=160, 3 terms
            #pragma unroll
            for (int u = 0; u < 2; ++u)
              #pragma unroll
              for (int nt = 0; nt < 2; ++nt) accw[u][nt] = zero4;
            #pragma unroll
            for (int kt = 0; kt < 5; ++kt) {
              #pragma unroll
              for (int u = 0; u < 2; ++u) {
                s16x8 xh = *(const s16x8*)&xc[(u*16 + r)*168 + kt*32 + g4*8];
                s16x8 xl = *(const s16x8*)&xc[(32 + u*16 + r)*168 + kt*32 + g4*8];
                accw[u][0] = MFMA_B16(xh, wbf[kt][0], accw[u][0]);
                accw[u][1] = MFMA_B16(xh, wbf[kt][1], accw[u][1]);
                accw[u][0] = MFMA_B16(xl, wbf[kt][0], accw[u][0]);
                accw[u][1] = MFMA_B16(xl, wbf[kt][1], accw[u][1]);
                accw[u][0] = MFMA_B16(xh, wlo[kt][0], accw[u][0]);
                accw[u][1] = MFMA_B16(xh, wlo[kt][1], accw[u][1]);
              }
            }
            PHASE1(0, 0);  BAR();
            PHASE1(0, 1);  BAR();
            PHASE1(1, 0);  BAR();
            PHASE1(1, 1);  BAR();
        }
        BAR();   // interval 256: L2 finishes step 255
    } else {
        // ---- L2 branch: stationary weights (N=32 slice) + stager state ----
        s16x8 w2f[2][3][2];   // L2 W hi/lo [nt][kt][sp] (kt2 = h2 block)
        #pragma unroll
        for (int nt = 0; nt < 2; ++nt)
          #pragma unroll
          for (int kt = 0; kt < 3; ++kt)
            #pragma unroll
            for (int sp = 0; sp < 2; ++sp)
              w2f[nt][kt][sp] = *(const s16x8*)(wsS + WS_W2 + sp*12288 +
                                                ((w & 3)*32 + nt*16 + r)*96 + kt*32 + g4*8);
        const float l2bi = b_ih2[u2i]      + b_hh2[u2i];
        const float l2bf = b_ih2[32 + u2i] + b_hh2[32 + u2i];
        const float l2bg = b_ih2[64 + u2i] + b_hh2[64 + u2i];
        const float l2bo = b_ih2[96 + u2i] + b_hh2[96 + u2i];

        const int t2 = tid & 255;
        const bool sv4 = (t2 < 24);
        int runm[5], km[5], offm[5];
        #pragma unroll
        for (int m = 0; m < 5; ++m) {
            int j = t2 + 256*m;
            int rn = j / 131;
            runm[m] = rn; km[m] = j - rn*131;
            offm[m] = (b0 + rn)*33536 + km[m];
        }
        float xr[5];
        #pragma unroll
        for (int m = 0; m < 5; ++m)    // prefetch chunk 0 of window 1
            xr[m] = (m < 4 || sv4) ? x[(size_t)(offm[m] + 4*131)] : 0.f;

        for (int w0 = 0; w0 < 64; ++w0) {
            short* xn = xbf + ((w0 & 1) ^ 1)*PLX;
            // steps handled here: 4*w0-1 .. 4*w0+2 (one behind L1)
            STAGE(0);  if (w0 > 0) PHASE2(1);  BAR();
            STAGE(1);  PHASE2(0);              BAR();
            STAGE(2);  PHASE2(1);              BAR();
            STAGE(3);  PHASE2(0);              BAR();
        }
        PHASE2(1);         // step 255
        BAR();             // interval 256
    }

    // ---- FC head (reuse gpre[0..255] as f32 stash of final h2) ----
    if (w >= 8) gpre[bq*32 + u2i] = h2last;
    __syncthreads();
    if (tid < 32) {
        int b = tid >> 2, cls = tid & 3;
        float s = b_fc[cls];
        #pragma unroll
        for (int k2 = 0; k2 < 32; ++k2) s += gpre[b*32 + k2] * W_fc[cls*32 + k2];
        out[(size_t)(b0 + b)*4 + cls] = s;
    }
}

extern "C" void kernel_launch(void* const* d_in, const int* in_sizes, int n_in,
                              void* d_out, int out_size, void* d_ws, size_t ws_size,
                              hipStream_t stream) {
    const float* x     = (const float*)d_in[0];
    const float* W_ih1 = (const float*)d_in[1];
    const float* W_hh1 = (const float*)d_in[2];
    const float* b_ih1 = (const float*)d_in[3];
    const float* b_hh1 = (const float*)d_in[4];
    const float* W_ih2 = (const float*)d_in[5];
    const float* W_hh2 = (const float*)d_in[6];
    const float* b_ih2 = (const float*)d_in[7];
    const float* b_hh2 = (const float*)d_in[8];
    const float* W_fc  = (const float*)d_in[9];
    const float* b_fc  = (const float*)d_in[10];
    float* out = (float*)d_out;
    short* wsS = (short*)d_ws;   // needs 278,528 bytes

    prep_w<<<(PREP_N + 255)/256, 256, 0, stream>>>(W_ih1, W_hh1, W_ih2, W_hh2,
                                                   b_ih1, b_hh1, wsS);
    lstm_mfma<<<B_TOT/8, NTHR, 0, stream>>>(x, wsS, b_ih2, b_hh2, W_fc, b_fc, out);
}